// Round 4
// baseline (480.492 us; speedup 1.0000x reference)
//
#include <hip/hip_runtime.h>
#include <hip/hip_bf16.h>

using bf16 = __hip_bfloat16;
typedef __attribute__((ext_vector_type(8))) short bf16x8;
typedef __attribute__((ext_vector_type(4))) float f32x4;
typedef __attribute__((ext_vector_type(16))) float f32x16;

#define LOG2E 1.4426950408889634f

__device__ inline short f2b(float f) {
  __hip_bfloat16 h = __float2bfloat16(f);
  return *reinterpret_cast<short*>(&h);
}
__device__ inline float b2f(short s) {
  unsigned int u = ((unsigned int)(unsigned short)s) << 16;
  float f;
  __builtin_memcpy(&f, &u, 4);
  return f;
}
__device__ inline unsigned pk2(float a, float b) {
  return (unsigned)(unsigned short)f2b(a) |
         ((unsigned)(unsigned short)f2b(b) << 16);
}

// ---------------- weight transpose + cast: in[K][N] f32 -> out[N][K] bf16 ----
__global__ __launch_bounds__(256) void transpose_cast_kernel(
    const float* __restrict__ in, bf16* __restrict__ out, int K, int N) {
  __shared__ float tile[32][33];
  int tx = threadIdx.x & 31;
  int ty = threadIdx.x >> 5;  // 0..7
  int n0 = blockIdx.x * 32, k0 = blockIdx.y * 32;
#pragma unroll
  for (int i = 0; i < 4; i++)
    tile[ty + i * 8][tx] = in[(size_t)(k0 + ty + i * 8) * N + n0 + tx];
  __syncthreads();
#pragma unroll
  for (int i = 0; i < 4; i++)
    out[(size_t)(n0 + ty + i * 8) * K + k0 + tx] =
        __float2bfloat16(tile[tx][ty + i * 8]);
}

// ---------------- V transpose: vt[bh][d][t] = qkv[b,t, 2048 + h*64 + d] -----
__global__ __launch_bounds__(256) void transpose_v_kernel(
    const bf16* __restrict__ qkv, bf16* __restrict__ vt) {
  __shared__ short tile[64][66];
  const int bh = blockIdx.y;
  const int b = bh >> 4, h = bh & 15;
  const int t0 = blockIdx.x * 64;
  const int tid = threadIdx.x;
  const int r = tid >> 3, c8 = (tid & 7) * 8;
#pragma unroll
  for (int p = 0; p < 2; p++) {
    int t = r + p * 32;
    bf16x8 v = *(const bf16x8*)&qkv[(size_t)(b * 2048 + t0 + t) * 3072 + 2048 +
                                    h * 64 + c8];
#pragma unroll
    for (int i = 0; i < 8; i++) tile[t][c8 + i] = v[i];
  }
  __syncthreads();
#pragma unroll
  for (int p = 0; p < 2; p++) {
    int d = r + p * 32;
    int tt = c8;
    bf16x8 o;
#pragma unroll
    for (int i = 0; i < 8; i++) o[i] = tile[tt + i][d];
    *(bf16x8*)&vt[(size_t)(bh * 64 + d) * 2048 + t0 + tt] = o;
  }
}

// ---------------- LayerNorm over C=1024, one block per row, bf16 out --------
__global__ __launch_bounds__(256) void ln_kernel(
    const float* __restrict__ x, const float* __restrict__ g,
    const float* __restrict__ b, bf16* __restrict__ out) {
  int row = blockIdx.x;
  const float4 v = ((const float4*)(x + (size_t)row * 1024))[threadIdx.x];
  float s = v.x + v.y + v.z + v.w;
  float ss = v.x * v.x + v.y * v.y + v.z * v.z + v.w * v.w;
#pragma unroll
  for (int off = 1; off < 64; off <<= 1) {
    s += __shfl_xor(s, off);
    ss += __shfl_xor(ss, off);
  }
  __shared__ float red[2][4];
  int w = threadIdx.x >> 6, lane = threadIdx.x & 63;
  if (lane == 0) { red[0][w] = s; red[1][w] = ss; }
  __syncthreads();
  s = red[0][0] + red[0][1] + red[0][2] + red[0][3];
  ss = red[1][0] + red[1][1] + red[1][2] + red[1][3];
  float mu = s * (1.0f / 1024.0f);
  float var = ss * (1.0f / 1024.0f) - mu * mu;
  float rstd = rsqrtf(var + 1e-5f);
  const float4 gv = ((const float4*)g)[threadIdx.x];
  const float4 bv = ((const float4*)b)[threadIdx.x];
  short4 o4;
  o4.x = f2b((v.x - mu) * rstd * gv.x + bv.x);
  o4.y = f2b((v.y - mu) * rstd * gv.y + bv.y);
  o4.z = f2b((v.z - mu) * rstd * gv.z + bv.z);
  o4.w = f2b((v.w - mu) * rstd * gv.w + bv.w);
  ((short4*)out)[(size_t)row * 256 + threadIdx.x] = o4;
}

// ---------------- 8-phase GEMM: C[M,N] = A[M,K]*Bt[N,K]^T + epilogue --------
// BM=128, BN=256, BK=64, 512 threads (8 waves, 2Mx4N). LDS XOR-swizzled
// (16B chunk ^= row&7, both-sides: pre-swizzled global src + swizzled read).
// Counted vmcnt: A-rounds lead by 2 tiles so the per-tile wait is vmcnt(2).
template <int MLO, int NLO>
__device__ inline void quad_mfma(f32x4 (&acc)[4][4], bf16x8 (&af)[2][2],
                                 bf16x8 (&bf)[2][2]) {
  __builtin_amdgcn_s_barrier();
  asm volatile("s_waitcnt lgkmcnt(0)" ::: "memory");
  __builtin_amdgcn_sched_barrier(0);
  __builtin_amdgcn_s_setprio(1);
#pragma unroll
  for (int mm = 0; mm < 2; mm++)
#pragma unroll
    for (int nn = 0; nn < 2; nn++)
#pragma unroll
      for (int ks = 0; ks < 2; ks++)
        acc[MLO + mm][NLO + nn] = __builtin_amdgcn_mfma_f32_16x16x32_bf16(
            af[mm][ks], bf[nn][ks], acc[MLO + mm][NLO + nn], 0, 0, 0);
  __builtin_amdgcn_s_setprio(0);
  __builtin_amdgcn_s_barrier();
}

template <int EPI>
__global__ __launch_bounds__(512, 1) void gemm_bt8_kernel(
    const bf16* __restrict__ A, const bf16* __restrict__ Bt,
    const float* __restrict__ bias, const float* __restrict__ res,
    void* __restrict__ out, int M, int N, int K) {
  __shared__ short As[2][128 * 64];
  __shared__ short Bs[2][256 * 64];
  const int tid = threadIdx.x;
  const int lane = tid & 63, wid = tid >> 6;
  const int wr = wid >> 2, wc = wid & 3;

  // bijective XCD swizzle; brow-fast decomposition keeps a B-panel per XCD
  const int nwg = gridDim.x;
  const int gy = M >> 7;
  const int flat = blockIdx.x;
  const int sw = (flat & 7) * (nwg >> 3) + (flat >> 3);
  const int bcol = sw / gy, brow = sw % gy;

  const int nk = K >> 6;

  auto stA = [&](int kt, int buf) {
#pragma unroll
    for (int r = 0; r < 2; r++) {
      const int row = tid >> 3;
      const int chs = (tid & 7) ^ (row & 7);
      const bf16* src =
          A + (size_t)(brow * 128 + r * 64 + row) * K + kt * 64 + chs * 8;
      __builtin_amdgcn_global_load_lds(
          (const __attribute__((address_space(1))) unsigned int*)src,
          (__attribute__((address_space(3))) unsigned int*)
              &As[buf][(r * 64 + wid * 8) * 64],
          16, 0, 0);
    }
  };
  auto stB = [&](int kt, int buf, int r0) {
#pragma unroll
    for (int rr = 0; rr < 2; rr++) {
      const int r = r0 + rr;
      const int row = tid >> 3;
      const int chs = (tid & 7) ^ (row & 7);
      const bf16* src =
          Bt + (size_t)(bcol * 256 + r * 64 + row) * K + kt * 64 + chs * 8;
      __builtin_amdgcn_global_load_lds(
          (const __attribute__((address_space(1))) unsigned int*)src,
          (__attribute__((address_space(3))) unsigned int*)
              &Bs[buf][(r * 64 + wid * 8) * 64],
          16, 0, 0);
    }
  };

  f32x4 acc[4][4] = {};
  bf16x8 af[2][2], bf0[2][2], bf1[2][2];
  int cur = 0;

  auto rdA = [&](int mh) {
#pragma unroll
    for (int mm = 0; mm < 2; mm++)
#pragma unroll
      for (int ks = 0; ks < 2; ks++) {
        const int row = wr * 64 + (mh * 2 + mm) * 16 + (lane & 15);
        const int ch = (ks * 4 + (lane >> 4)) ^ (row & 7);
        af[mm][ks] = *(const bf16x8*)&As[cur][row * 64 + ch * 8];
      }
  };
  auto rdB = [&](bf16x8(&bf)[2][2], int nh) {
#pragma unroll
    for (int nn = 0; nn < 2; nn++)
#pragma unroll
      for (int ks = 0; ks < 2; ks++) {
        const int row = wc * 64 + (nh * 2 + nn) * 16 + (lane & 15);
        const int ch = (ks * 4 + (lane >> 4)) ^ (row & 7);
        bf[nn][ks] = *(const bf16x8*)&Bs[cur][row * 64 + ch * 8];
      }
  };

  // prologue: tile0 fully, tile1's A rounds (lead by 2); wait leaves 2 in flight
  stA(0, 0);
  stB(0, 0, 0);
  stB(0, 0, 2);
  stA(1, 1);
  asm volatile("s_waitcnt vmcnt(2)" ::: "memory");
  __builtin_amdgcn_s_barrier();

  for (int t = 0; t < nk; t++) {
    cur = t & 1;
    const int nxt = cur ^ 1;
    // P0: read A[mh0], B[nh0]; stage next-tile B rounds 0,1
    rdA(0);
    rdB(bf0, 0);
    if (t + 1 < nk) stB(t + 1, nxt, 0);
    quad_mfma<0, 0>(acc, af, bf0);
    // P1: read B[nh1]; stage next-tile B rounds 2,3
    rdB(bf1, 1);
    if (t + 1 < nk) stB(t + 1, nxt, 2);
    quad_mfma<0, 2>(acc, af, bf1);
    // P2: read A[mh1]
    rdA(1);
    quad_mfma<2, 2>(acc, af, bf1);
    // P3: stage A for tile t+2 (into cur, just freed); counted wait for t+1
    if (t + 2 < nk) {
      stA(t + 2, cur);
      asm volatile("s_waitcnt vmcnt(2)" ::: "memory");
    } else if (t + 1 < nk) {
      asm volatile("s_waitcnt vmcnt(0)" ::: "memory");
    }
    quad_mfma<2, 0>(acc, af, bf0);
  }

  // epilogue
#pragma unroll
  for (int m = 0; m < 4; m++)
#pragma unroll
    for (int n = 0; n < 4; n++) {
      int gr0 = brow * 128 + wr * 64 + m * 16 + (lane >> 4) * 4;
      int gc = bcol * 256 + wc * 64 + n * 16 + (lane & 15);
      float bia = bias[gc];
#pragma unroll
      for (int j = 0; j < 4; j++) {
        float v = acc[m][n][j] + bia;
        size_t idx = (size_t)(gr0 + j) * N + gc;
        if constexpr (EPI == 0) {
          ((bf16*)out)[idx] = __float2bfloat16(v);
        } else if constexpr (EPI == 1) {
          ((float*)out)[idx] = v + res[idx];
        } else {
          float u = 0.7978845608028654f * (v + 0.044715f * v * v * v);
          float t2 = exp2f(u * (2.0f * LOG2E));
          float th = 1.0f - 2.0f / (t2 + 1.0f);
          ((bf16*)out)[idx] = __float2bfloat16(0.5f * v * (1.0f + th));
        }
      }
    }
}

// ---------------- Flash attention: swapped-QK^T 32x32 structure -------------
__global__ __launch_bounds__(256) void attn_kernel(
    const bf16* __restrict__ qkv, const bf16* __restrict__ vt,
    bf16* __restrict__ attn) {
  const int bh = blockIdx.x;  // 0..63
  const int qt = blockIdx.y;  // 0..15
  const int b = bh >> 4, h = bh & 15;
  const int tid = threadIdx.x, w = tid >> 6, lane = tid & 63;
  const int col = lane & 31;
  const int hi = lane >> 5;

  __shared__ short Kl[64 * 64];  // [kv][d], XOR-swizzled 16B chunks
  __shared__ short Vl[64 * 64];  // [d][kv], XOR-swizzled 16B chunks

  const int qbase = qt * 128 + w * 32;
  const int qglob = qbase + col;
  const size_t qrow = (size_t)(b * 2048 + qglob);

  bf16x8 qf[4];
#pragma unroll
  for (int dks = 0; dks < 4; dks++) {
    bf16x8 raw =
        *(const bf16x8*)&qkv[qrow * 3072 + h * 64 + dks * 16 + hi * 8];
#pragma unroll
    for (int i = 0; i < 8; i++) qf[dks][i] = f2b(b2f(raw[i]) * 0.125f);
  }

  f32x16 ot[2] = {};
  float m = -1e30f, l = 0.0f;

  const int ktend = qt * 2 + 1;
  for (int kt = 0; kt <= ktend; kt++) {
    const int kv0 = kt * 64;
    __syncthreads();
#pragma unroll
    for (int j = 0; j < 2; j++) {
      int c = (j * 4 + w) * 64 + lane;
      int row = c >> 3;
      int sw8 = ((c & 7) ^ (row & 7)) * 8;
      const bf16* gk =
          qkv + (size_t)(b * 2048 + kv0 + row) * 3072 + 1024 + h * 64 + sw8;
      __builtin_amdgcn_global_load_lds(
          (const __attribute__((address_space(1))) unsigned int*)gk,
          (__attribute__((address_space(3))) unsigned int*)(Kl + (j * 4 + w) * 512),
          16, 0, 0);
      const bf16* gv = vt + (size_t)(bh * 64 + row) * 2048 + kv0 + sw8;
      __builtin_amdgcn_global_load_lds(
          (const __attribute__((address_space(1))) unsigned int*)gv,
          (__attribute__((address_space(3))) unsigned int*)(Vl + (j * 4 + w) * 512),
          16, 0, 0);
    }
    __syncthreads();

    if (kv0 <= qbase + 31) {
      f32x16 st[2] = {};
#pragma unroll
      for (int s = 0; s < 2; s++) {
        int kvrow = s * 32 + col;
        int swz = kvrow & 7;
#pragma unroll
        for (int dks = 0; dks < 4; dks++) {
          int ch = (dks * 2 + hi) ^ swz;
          bf16x8 kf = *(const bf16x8*)&Kl[kvrow * 64 + ch * 8];
          st[s] = __builtin_amdgcn_mfma_f32_32x32x16_bf16(kf, qf[dks], st[s],
                                                          0, 0, 0);
        }
      }
      if (kv0 + 63 > qbase) {
#pragma unroll
        for (int s = 0; s < 2; s++)
#pragma unroll
          for (int r = 0; r < 16; r++) {
            int kv = kv0 + s * 32 + (r & 3) + 8 * (r >> 2) + 4 * hi;
            if (kv > qglob) st[s][r] = -1e30f;
          }
      }
      float pmax = -1e30f;
#pragma unroll
      for (int s = 0; s < 2; s++)
#pragma unroll
        for (int r = 0; r < 16; r++) pmax = fmaxf(pmax, st[s][r]);
      pmax = fmaxf(pmax, __shfl_xor(pmax, 32));
      float mnew = fmaxf(m, pmax);
      float corr = exp2f((m - mnew) * LOG2E);
      m = mnew;
      float rs = 0.0f;
#pragma unroll
      for (int s = 0; s < 2; s++)
#pragma unroll
        for (int r = 0; r < 16; r++) {
          float pv = exp2f((st[s][r] - mnew) * LOG2E);
          st[s][r] = pv;
          rs += pv;
        }
      rs += __shfl_xor(rs, 32);
      l = l * corr + rs;
#pragma unroll
      for (int s = 0; s < 2; s++)
#pragma unroll
        for (int r = 0; r < 16; r++) ot[s][r] *= corr;

#pragma unroll
      for (int sub = 0; sub < 2; sub++) {
#pragma unroll
        for (int kl = 0; kl < 2; kl++) {
          unsigned A0 = pk2(st[sub][kl * 8 + 0], st[sub][kl * 8 + 1]);
          unsigned A1 = pk2(st[sub][kl * 8 + 2], st[sub][kl * 8 + 3]);
          unsigned B0 = pk2(st[sub][kl * 8 + 4], st[sub][kl * 8 + 5]);
          unsigned B1 = pk2(st[sub][kl * 8 + 6], st[sub][kl * 8 + 7]);
          unsigned sA0 = (unsigned)__shfl_xor((int)A0, 32);
          unsigned sA1 = (unsigned)__shfl_xor((int)A1, 32);
          unsigned sB0 = (unsigned)__shfl_xor((int)B0, 32);
          unsigned sB1 = (unsigned)__shfl_xor((int)B1, 32);
          union { unsigned u[4]; bf16x8 v; } pf;
          pf.u[0] = hi ? sB0 : A0;
          pf.u[1] = hi ? sB1 : A1;
          pf.u[2] = hi ? B0 : sA0;
          pf.u[3] = hi ? B1 : sA1;
          int ks = sub * 2 + kl;
#pragma unroll
          for (int ds = 0; ds < 2; ds++) {
            int drow = ds * 32 + col;
            int ch = (ks * 2 + hi) ^ (drow & 7);
            bf16x8 vf = *(const bf16x8*)&Vl[drow * 64 + ch * 8];
            ot[ds] = __builtin_amdgcn_mfma_f32_32x32x16_bf16(vf, pf.v, ot[ds],
                                                             0, 0, 0);
          }
        }
      }
    }
  }

  float rl = 1.0f / l;
#pragma unroll
  for (int ds = 0; ds < 2; ds++)
#pragma unroll
    for (int j = 0; j < 4; j++) {
      ushort4 o4;
      o4.x = (unsigned short)f2b(ot[ds][4 * j + 0] * rl);
      o4.y = (unsigned short)f2b(ot[ds][4 * j + 1] * rl);
      o4.z = (unsigned short)f2b(ot[ds][4 * j + 2] * rl);
      o4.w = (unsigned short)f2b(ot[ds][4 * j + 3] * rl);
      *(ushort4*)&attn[qrow * 1024 + h * 64 + 32 * ds + 8 * j + 4 * hi] = o4;
    }
}

// ---------------- host-side orchestration -----------------------------------
extern "C" void kernel_launch(void* const* d_in, const int* in_sizes, int n_in,
                              void* d_out, int out_size, void* d_ws,
                              size_t ws_size, hipStream_t stream) {
  (void)in_sizes; (void)n_in; (void)out_size; (void)ws_size;
  const float* x      = (const float*)d_in[0];
  const float* ln1_g  = (const float*)d_in[1];
  const float* ln1_b  = (const float*)d_in[2];
  const float* w_qkv  = (const float*)d_in[3];
  const float* b_qkv  = (const float*)d_in[4];
  const float* w_o    = (const float*)d_in[5];
  const float* b_o    = (const float*)d_in[6];
  const float* ln2_g  = (const float*)d_in[7];
  const float* ln2_b  = (const float*)d_in[8];
  const float* w_fc   = (const float*)d_in[9];
  const float* b_fc   = (const float*)d_in[10];
  const float* w_proj = (const float*)d_in[11];
  const float* b_proj = (const float*)d_in[12];
  float* out = (float*)d_out;

  char* ws = (char*)d_ws;
  bf16* wt_qkv  = (bf16*)(ws + 0);          //  6.0 MB  [3072][1024]
  bf16* wt_o    = (bf16*)(ws + 6291456);    //  2.0 MB  [1024][1024]
  bf16* wt_fc   = (bf16*)(ws + 8388608);    //  8.0 MB  [4096][1024]
  bf16* wt_proj = (bf16*)(ws + 16777216);   //  8.0 MB  [1024][4096]
  float* x1     = (float*)(ws + 25165824);  // 32.0 MB  [8192][1024] f32
  bf16* vtb     = (bf16*)(ws + 25165824);   // 16.0 MB  vt (dead before x1)
  bf16* slotA   = (bf16*)(ws + 58720256);   // 16.0 MB  h / attn / h2
  bf16* qkvb    = (bf16*)(ws + 75497472);   // 48.0 MB  [8192][3072]
  bf16* gbuf    = (bf16*)(ws + 75497472);   // 64.0 MB  [8192][4096] (reuse)

  dim3 blk(256);
  transpose_cast_kernel<<<dim3(3072 / 32, 1024 / 32), blk, 0, stream>>>(
      w_qkv, wt_qkv, 1024, 3072);
  transpose_cast_kernel<<<dim3(1024 / 32, 1024 / 32), blk, 0, stream>>>(
      w_o, wt_o, 1024, 1024);
  transpose_cast_kernel<<<dim3(4096 / 32, 1024 / 32), blk, 0, stream>>>(
      w_fc, wt_fc, 1024, 4096);
  transpose_cast_kernel<<<dim3(1024 / 32, 4096 / 32), blk, 0, stream>>>(
      w_proj, wt_proj, 4096, 1024);

  ln_kernel<<<8192, blk, 0, stream>>>(x, ln1_g, ln1_b, slotA);
  // qkv = h @ w_qkv + b_qkv : M=8192 N=3072 K=1024 -> 64*12=768 blocks
  gemm_bt8_kernel<0><<<dim3(768), dim3(512), 0, stream>>>(
      slotA, wt_qkv, b_qkv, nullptr, qkvb, 8192, 3072, 1024);
  transpose_v_kernel<<<dim3(32, 64), blk, 0, stream>>>(qkvb, vtb);
  attn_kernel<<<dim3(64, 16), blk, 0, stream>>>(qkvb, vtb, slotA);
  // x1 = attn @ w_o + b_o + x : N=1024 -> 64*4=256 blocks
  gemm_bt8_kernel<1><<<dim3(256), dim3(512), 0, stream>>>(
      slotA, wt_o, b_o, x, x1, 8192, 1024, 1024);
  ln_kernel<<<8192, blk, 0, stream>>>(x1, ln2_g, ln2_b, slotA);
  // g = gelu(h2 @ w_fc + b_fc) : N=4096 -> 64*16=1024 blocks
  gemm_bt8_kernel<2><<<dim3(1024), dim3(512), 0, stream>>>(
      slotA, wt_fc, b_fc, nullptr, gbuf, 8192, 4096, 1024);
  // out = g @ w_proj + b_proj + x1 : N=1024 K=4096 -> 256 blocks
  gemm_bt8_kernel<1><<<dim3(256), dim3(512), 0, stream>>>(
      gbuf, wt_proj, b_proj, x1, out, 8192, 1024, 4096);
}

// Round 5
// 444.667 us; speedup vs baseline: 1.0806x; 1.0806x over previous
//
#include <hip/hip_runtime.h>
#include <hip/hip_bf16.h>

using bf16 = __hip_bfloat16;
typedef __attribute__((ext_vector_type(8))) short bf16x8;
typedef __attribute__((ext_vector_type(4))) float f32x4;
typedef __attribute__((ext_vector_type(16))) float f32x16;

#define LOG2E 1.4426950408889634f

__device__ inline short f2b(float f) {
  __hip_bfloat16 h = __float2bfloat16(f);
  return *reinterpret_cast<short*>(&h);
}
__device__ inline float b2f(short s) {
  unsigned int u = ((unsigned int)(unsigned short)s) << 16;
  float f;
  __builtin_memcpy(&f, &u, 4);
  return f;
}
__device__ inline unsigned pk2(float a, float b) {
  return (unsigned)(unsigned short)f2b(a) |
         ((unsigned)(unsigned short)f2b(b) << 16);
}

// ---------------- weight transpose + cast: in[K][N] f32 -> out[N][K] bf16 ----
__global__ __launch_bounds__(256) void transpose_cast_kernel(
    const float* __restrict__ in, bf16* __restrict__ out, int K, int N) {
  __shared__ float tile[32][33];
  int tx = threadIdx.x & 31;
  int ty = threadIdx.x >> 5;
  int n0 = blockIdx.x * 32, k0 = blockIdx.y * 32;
#pragma unroll
  for (int i = 0; i < 4; i++)
    tile[ty + i * 8][tx] = in[(size_t)(k0 + ty + i * 8) * N + n0 + tx];
  __syncthreads();
#pragma unroll
  for (int i = 0; i < 4; i++)
    out[(size_t)(n0 + ty + i * 8) * K + k0 + tx] =
        __float2bfloat16(tile[tx][ty + i * 8]);
}

// ---------------- V transpose: vt[bh][d][t] ---------------------------------
__global__ __launch_bounds__(256) void transpose_v_kernel(
    const bf16* __restrict__ qkv, bf16* __restrict__ vt) {
  __shared__ short tile[64][66];
  const int bh = blockIdx.y;
  const int b = bh >> 4, h = bh & 15;
  const int t0 = blockIdx.x * 64;
  const int tid = threadIdx.x;
  const int r = tid >> 3, c8 = (tid & 7) * 8;
#pragma unroll
  for (int p = 0; p < 2; p++) {
    int t = r + p * 32;
    bf16x8 v = *(const bf16x8*)&qkv[(size_t)(b * 2048 + t0 + t) * 3072 + 2048 +
                                    h * 64 + c8];
#pragma unroll
    for (int i = 0; i < 8; i++) tile[t][c8 + i] = v[i];
  }
  __syncthreads();
#pragma unroll
  for (int p = 0; p < 2; p++) {
    int d = r + p * 32;
    int tt = c8;
    bf16x8 o;
#pragma unroll
    for (int i = 0; i < 8; i++) o[i] = tile[tt + i][d];
    *(bf16x8*)&vt[(size_t)(bh * 64 + d) * 2048 + t0 + tt] = o;
  }
}

// ---------------- LayerNorm (LN1): f32 in -> bf16 out -----------------------
__global__ __launch_bounds__(256) void ln_kernel(
    const float* __restrict__ x, const float* __restrict__ g,
    const float* __restrict__ b, bf16* __restrict__ out) {
  int row = blockIdx.x;
  const float4 v = ((const float4*)(x + (size_t)row * 1024))[threadIdx.x];
  float s = v.x + v.y + v.z + v.w;
  float ss = v.x * v.x + v.y * v.y + v.z * v.z + v.w * v.w;
#pragma unroll
  for (int off = 1; off < 64; off <<= 1) {
    s += __shfl_xor(s, off);
    ss += __shfl_xor(ss, off);
  }
  __shared__ float red[2][4];
  int w = threadIdx.x >> 6, lane = threadIdx.x & 63;
  if (lane == 0) { red[0][w] = s; red[1][w] = ss; }
  __syncthreads();
  s = red[0][0] + red[0][1] + red[0][2] + red[0][3];
  ss = red[1][0] + red[1][1] + red[1][2] + red[1][3];
  float mu = s * (1.0f / 1024.0f);
  float var = ss * (1.0f / 1024.0f) - mu * mu;
  float rstd = rsqrtf(var + 1e-5f);
  const float4 gv = ((const float4*)g)[threadIdx.x];
  const float4 bv = ((const float4*)b)[threadIdx.x];
  short4 o4;
  o4.x = f2b((v.x - mu) * rstd * gv.x + bv.x);
  o4.y = f2b((v.y - mu) * rstd * gv.y + bv.y);
  o4.z = f2b((v.z - mu) * rstd * gv.z + bv.z);
  o4.w = f2b((v.w - mu) * rstd * gv.w + bv.w);
  ((short4*)out)[(size_t)row * 256 + threadIdx.x] = o4;
}

// ---------------- fused: x1 = p0+p1+b_o+x ; h2 = LN2(x1) --------------------
__global__ __launch_bounds__(256) void fused_ln_kernel(
    const float* __restrict__ p0, const float* __restrict__ p1,
    const float* __restrict__ bo, const float* __restrict__ x,
    const float* __restrict__ g, const float* __restrict__ bln,
    float* __restrict__ x1, bf16* __restrict__ h2) {
  int row = blockIdx.x;
  size_t base = (size_t)row * 256 + threadIdx.x;
  float4 a = ((const float4*)p0)[base];
  float4 c = ((const float4*)p1)[base];
  float4 xr = ((const float4*)x)[base];
  float4 bo4 = ((const float4*)bo)[threadIdx.x];
  float4 v;
  v.x = a.x + c.x + xr.x + bo4.x;
  v.y = a.y + c.y + xr.y + bo4.y;
  v.z = a.z + c.z + xr.z + bo4.z;
  v.w = a.w + c.w + xr.w + bo4.w;
  ((float4*)x1)[base] = v;
  float s = v.x + v.y + v.z + v.w;
  float ss = v.x * v.x + v.y * v.y + v.z * v.z + v.w * v.w;
#pragma unroll
  for (int off = 1; off < 64; off <<= 1) {
    s += __shfl_xor(s, off);
    ss += __shfl_xor(ss, off);
  }
  __shared__ float red[2][4];
  int w = threadIdx.x >> 6, lane = threadIdx.x & 63;
  if (lane == 0) { red[0][w] = s; red[1][w] = ss; }
  __syncthreads();
  s = red[0][0] + red[0][1] + red[0][2] + red[0][3];
  ss = red[1][0] + red[1][1] + red[1][2] + red[1][3];
  float mu = s * (1.0f / 1024.0f);
  float var = ss * (1.0f / 1024.0f) - mu * mu;
  float rstd = rsqrtf(var + 1e-5f);
  const float4 gv = ((const float4*)g)[threadIdx.x];
  const float4 bv = ((const float4*)bln)[threadIdx.x];
  short4 o4;
  o4.x = f2b((v.x - mu) * rstd * gv.x + bv.x);
  o4.y = f2b((v.y - mu) * rstd * gv.y + bv.y);
  o4.z = f2b((v.z - mu) * rstd * gv.z + bv.z);
  o4.w = f2b((v.w - mu) * rstd * gv.w + bv.w);
  ((short4*)h2)[base] = o4;
}

// ---------------- fused: out = q0(in d_out) + q1 + b_proj + x1 --------------
__global__ __launch_bounds__(256) void fused_add_kernel(
    float* __restrict__ out, const float* __restrict__ q1,
    const float* __restrict__ x1, const float* __restrict__ bp, int n4) {
  for (int i = blockIdx.x * 256 + threadIdx.x; i < n4; i += gridDim.x * 256) {
    float4 a = ((const float4*)out)[i];
    float4 c = ((const float4*)q1)[i];
    float4 xr = ((const float4*)x1)[i];
    float4 b4 = ((const float4*)bp)[i & 255];
    float4 v;
    v.x = a.x + c.x + xr.x + b4.x;
    v.y = a.y + c.y + xr.y + b4.y;
    v.z = a.z + c.z + xr.z + b4.z;
    v.w = a.w + c.w + xr.w + b4.w;
    ((float4*)out)[i] = v;
  }
}

// ---------------- 256x256 GEMM, BK=64, 8 waves (2Mx4N, per-wave 128x64) -----
// C = A[M,K] * Bt[N,K]^T. LDS XOR-swizzled both sides. 2 phases/K-tile,
// 32 MFMA each; B-frags register-resident per tile; full-tile prefetch at P0.
// EPI 0: bf16 = acc+bias ; EPI 2: bf16 = gelu(acc+bias) ;
// EPI 3: f32 raw partial -> out0/out1 selected by split-K half.
template <int EPI>
__global__ __launch_bounds__(512, 1) void gemm256_kernel(
    const bf16* __restrict__ A, const bf16* __restrict__ Bt,
    const float* __restrict__ bias, float* __restrict__ out0,
    float* __restrict__ out1, void* __restrict__ outv, int M, int N, int Kfull,
    int Ksub, int ntiles) {
  __shared__ short As[2][256 * 64];
  __shared__ short Bs[2][256 * 64];
  const int tid = threadIdx.x;
  const int lane = tid & 63, wid = tid >> 6;
  const int wr = wid >> 2, wc = wid & 3;

  const int nwg = gridDim.x;
  const int flat = blockIdx.x;
  const int sw = (flat & 7) * (nwg >> 3) + (flat >> 3);  // bijective, nwg%8==0
  const int kq = sw / ntiles;
  const int tile = sw % ntiles;
  const int gy = M >> 8;
  const int bcol = tile / gy, brow = tile % gy;
  const int koff = kq * Ksub;
  const int nk = Ksub >> 6;

  const int srow = tid >> 3;
  const int schs = (tid & 7) ^ (srow & 7);

  auto stA = [&](int kt, int buf) {
#pragma unroll
    for (int r = 0; r < 4; r++) {
      const bf16* src = A + (size_t)(brow * 256 + r * 64 + srow) * Kfull +
                        koff + kt * 64 + schs * 8;
      __builtin_amdgcn_global_load_lds(
          (const __attribute__((address_space(1))) unsigned int*)src,
          (__attribute__((address_space(3))) unsigned int*)
              &As[buf][(r * 64 + wid * 8) * 64],
          16, 0, 0);
    }
  };
  auto stB = [&](int kt, int buf) {
#pragma unroll
    for (int r = 0; r < 4; r++) {
      const bf16* src = Bt + (size_t)(bcol * 256 + r * 64 + srow) * Kfull +
                        koff + kt * 64 + schs * 8;
      __builtin_amdgcn_global_load_lds(
          (const __attribute__((address_space(1))) unsigned int*)src,
          (__attribute__((address_space(3))) unsigned int*)
              &Bs[buf][(r * 64 + wid * 8) * 64],
          16, 0, 0);
    }
  };

  f32x4 acc[8][4] = {};
  bf16x8 af[4][2], bfr[4][2];

  auto rdB = [&](int cur) {
#pragma unroll
    for (int nn = 0; nn < 4; nn++)
#pragma unroll
      for (int ks = 0; ks < 2; ks++) {
        const int row = wc * 64 + nn * 16 + (lane & 15);
        const int ch = (ks * 4 + (lane >> 4)) ^ (row & 7);
        bfr[nn][ks] = *(const bf16x8*)&Bs[cur][row * 64 + ch * 8];
      }
  };
  auto rdA = [&](int cur, int mh) {
#pragma unroll
    for (int mm = 0; mm < 4; mm++)
#pragma unroll
      for (int ks = 0; ks < 2; ks++) {
        const int row = wr * 128 + mh * 64 + mm * 16 + (lane & 15);
        const int ch = (ks * 4 + (lane >> 4)) ^ (row & 7);
        af[mm][ks] = *(const bf16x8*)&As[cur][row * 64 + ch * 8];
      }
  };

  // prologue: stage tile 0, drain, barrier
  stA(0, 0);
  stB(0, 0);
  asm volatile("s_waitcnt vmcnt(0)" ::: "memory");
  __builtin_amdgcn_s_barrier();

  for (int t = 0; t < nk; t++) {
    const int cur = t & 1, nxt = cur ^ 1;
    // P0: read B(all)+A(half0); prefetch full next tile; MFMA half0
    rdB(cur);
    rdA(cur, 0);
    if (t + 1 < nk) {
      stA(t + 1, nxt);
      stB(t + 1, nxt);
    }
    __builtin_amdgcn_s_barrier();
    asm volatile("s_waitcnt lgkmcnt(0)" ::: "memory");
    __builtin_amdgcn_sched_barrier(0);
    __builtin_amdgcn_s_setprio(1);
#pragma unroll
    for (int mm = 0; mm < 4; mm++)
#pragma unroll
      for (int nn = 0; nn < 4; nn++)
#pragma unroll
        for (int ks = 0; ks < 2; ks++)
          acc[mm][nn] = __builtin_amdgcn_mfma_f32_16x16x32_bf16(
              af[mm][ks], bfr[nn][ks], acc[mm][nn], 0, 0, 0);
    __builtin_amdgcn_s_setprio(0);
    __builtin_amdgcn_s_barrier();
    // P1: read A(half1); MFMA half1; counted drain; barrier
    rdA(cur, 1);
    asm volatile("s_waitcnt lgkmcnt(0)" ::: "memory");
    __builtin_amdgcn_sched_barrier(0);
    __builtin_amdgcn_s_setprio(1);
#pragma unroll
    for (int mm = 0; mm < 4; mm++)
#pragma unroll
      for (int nn = 0; nn < 4; nn++)
#pragma unroll
        for (int ks = 0; ks < 2; ks++)
          acc[4 + mm][nn] = __builtin_amdgcn_mfma_f32_16x16x32_bf16(
              af[mm][ks], bfr[nn][ks], acc[4 + mm][nn], 0, 0, 0);
    __builtin_amdgcn_s_setprio(0);
    if (t + 1 < nk) asm volatile("s_waitcnt vmcnt(0)" ::: "memory");
    __builtin_amdgcn_s_barrier();
  }

  // epilogue
#pragma unroll
  for (int m = 0; m < 8; m++)
#pragma unroll
    for (int n = 0; n < 4; n++) {
      int gr0 = brow * 256 + wr * 128 + m * 16 + (lane >> 4) * 4;
      int gc = bcol * 256 + wc * 64 + n * 16 + (lane & 15);
      if constexpr (EPI == 3) {
        float* po = kq ? out1 : out0;
#pragma unroll
        for (int j = 0; j < 4; j++)
          po[(size_t)(gr0 + j) * N + gc] = acc[m][n][j];
      } else {
        float bia = bias[gc];
#pragma unroll
        for (int j = 0; j < 4; j++) {
          float v = acc[m][n][j] + bia;
          size_t idx = (size_t)(gr0 + j) * N + gc;
          if constexpr (EPI == 0) {
            ((bf16*)outv)[idx] = __float2bfloat16(v);
          } else {
            float u = 0.7978845608028654f * (v + 0.044715f * v * v * v);
            float t2 = exp2f(u * (2.0f * LOG2E));
            float th = 1.0f - 2.0f / (t2 + 1.0f);
            ((bf16*)outv)[idx] = __float2bfloat16(0.5f * v * (1.0f + th));
          }
        }
      }
    }
}

// ---------------- Flash attention: swapped-QK^T 32x32 structure -------------
__global__ __launch_bounds__(256) void attn_kernel(
    const bf16* __restrict__ qkv, const bf16* __restrict__ vt,
    bf16* __restrict__ attn) {
  const int bh = blockIdx.x;
  const int qt = blockIdx.y;
  const int b = bh >> 4, h = bh & 15;
  const int tid = threadIdx.x, w = tid >> 6, lane = tid & 63;
  const int col = lane & 31;
  const int hi = lane >> 5;

  __shared__ short Kl[64 * 64];
  __shared__ short Vl[64 * 64];

  const int qbase = qt * 128 + w * 32;
  const int qglob = qbase + col;
  const size_t qrow = (size_t)(b * 2048 + qglob);

  bf16x8 qf[4];
#pragma unroll
  for (int dks = 0; dks < 4; dks++) {
    bf16x8 raw =
        *(const bf16x8*)&qkv[qrow * 3072 + h * 64 + dks * 16 + hi * 8];
#pragma unroll
    for (int i = 0; i < 8; i++) qf[dks][i] = f2b(b2f(raw[i]) * 0.125f);
  }

  f32x16 ot[2] = {};
  float m = -1e30f, l = 0.0f;

  const int ktend = qt * 2 + 1;
  for (int kt = 0; kt <= ktend; kt++) {
    const int kv0 = kt * 64;
    __syncthreads();
#pragma unroll
    for (int j = 0; j < 2; j++) {
      int c = (j * 4 + w) * 64 + lane;
      int row = c >> 3;
      int sw8 = ((c & 7) ^ (row & 7)) * 8;
      const bf16* gk =
          qkv + (size_t)(b * 2048 + kv0 + row) * 3072 + 1024 + h * 64 + sw8;
      __builtin_amdgcn_global_load_lds(
          (const __attribute__((address_space(1))) unsigned int*)gk,
          (__attribute__((address_space(3))) unsigned int*)(Kl + (j * 4 + w) * 512),
          16, 0, 0);
      const bf16* gv = vt + (size_t)(bh * 64 + row) * 2048 + kv0 + sw8;
      __builtin_amdgcn_global_load_lds(
          (const __attribute__((address_space(1))) unsigned int*)gv,
          (__attribute__((address_space(3))) unsigned int*)(Vl + (j * 4 + w) * 512),
          16, 0, 0);
    }
    __syncthreads();

    if (kv0 <= qbase + 31) {
      f32x16 st[2] = {};
#pragma unroll
      for (int s = 0; s < 2; s++) {
        int kvrow = s * 32 + col;
        int swz = kvrow & 7;
#pragma unroll
        for (int dks = 0; dks < 4; dks++) {
          int ch = (dks * 2 + hi) ^ swz;
          bf16x8 kf = *(const bf16x8*)&Kl[kvrow * 64 + ch * 8];
          st[s] = __builtin_amdgcn_mfma_f32_32x32x16_bf16(kf, qf[dks], st[s],
                                                          0, 0, 0);
        }
      }
      if (kv0 + 63 > qbase) {
#pragma unroll
        for (int s = 0; s < 2; s++)
#pragma unroll
          for (int r = 0; r < 16; r++) {
            int kv = kv0 + s * 32 + (r & 3) + 8 * (r >> 2) + 4 * hi;
            if (kv > qglob) st[s][r] = -1e30f;
          }
      }
      float pmax = -1e30f;
#pragma unroll
      for (int s = 0; s < 2; s++)
#pragma unroll
        for (int r = 0; r < 16; r++) pmax = fmaxf(pmax, st[s][r]);
      pmax = fmaxf(pmax, __shfl_xor(pmax, 32));
      float mnew = fmaxf(m, pmax);
      float corr = exp2f((m - mnew) * LOG2E);
      m = mnew;
      float rs = 0.0f;
#pragma unroll
      for (int s = 0; s < 2; s++)
#pragma unroll
        for (int r = 0; r < 16; r++) {
          float pv = exp2f((st[s][r] - mnew) * LOG2E);
          st[s][r] = pv;
          rs += pv;
        }
      rs += __shfl_xor(rs, 32);
      l = l * corr + rs;
#pragma unroll
      for (int s = 0; s < 2; s++)
#pragma unroll
        for (int r = 0; r < 16; r++) ot[s][r] *= corr;

#pragma unroll
      for (int sub = 0; sub < 2; sub++) {
#pragma unroll
        for (int kl = 0; kl < 2; kl++) {
          unsigned A0 = pk2(st[sub][kl * 8 + 0], st[sub][kl * 8 + 1]);
          unsigned A1 = pk2(st[sub][kl * 8 + 2], st[sub][kl * 8 + 3]);
          unsigned B0 = pk2(st[sub][kl * 8 + 4], st[sub][kl * 8 + 5]);
          unsigned B1 = pk2(st[sub][kl * 8 + 6], st[sub][kl * 8 + 7]);
          unsigned sA0 = (unsigned)__shfl_xor((int)A0, 32);
          unsigned sA1 = (unsigned)__shfl_xor((int)A1, 32);
          unsigned sB0 = (unsigned)__shfl_xor((int)B0, 32);
          unsigned sB1 = (unsigned)__shfl_xor((int)B1, 32);
          union { unsigned u[4]; bf16x8 v; } pf;
          pf.u[0] = hi ? sB0 : A0;
          pf.u[1] = hi ? sB1 : A1;
          pf.u[2] = hi ? B0 : sA0;
          pf.u[3] = hi ? B1 : sA1;
          int ks = sub * 2 + kl;
#pragma unroll
          for (int ds = 0; ds < 2; ds++) {
            int drow = ds * 32 + col;
            int ch = (ks * 2 + hi) ^ (drow & 7);
            bf16x8 vf = *(const bf16x8*)&Vl[drow * 64 + ch * 8];
            ot[ds] = __builtin_amdgcn_mfma_f32_32x32x16_bf16(vf, pf.v, ot[ds],
                                                             0, 0, 0);
          }
        }
      }
    }
  }

  float rl = 1.0f / l;
#pragma unroll
  for (int ds = 0; ds < 2; ds++)
#pragma unroll
    for (int j = 0; j < 4; j++) {
      ushort4 o4;
      o4.x = (unsigned short)f2b(ot[ds][4 * j + 0] * rl);
      o4.y = (unsigned short)f2b(ot[ds][4 * j + 1] * rl);
      o4.z = (unsigned short)f2b(ot[ds][4 * j + 2] * rl);
      o4.w = (unsigned short)f2b(ot[ds][4 * j + 3] * rl);
      *(ushort4*)&attn[qrow * 1024 + h * 64 + 32 * ds + 8 * j + 4 * hi] = o4;
    }
}

// ---------------- host-side orchestration -----------------------------------
extern "C" void kernel_launch(void* const* d_in, const int* in_sizes, int n_in,
                              void* d_out, int out_size, void* d_ws,
                              size_t ws_size, hipStream_t stream) {
  (void)in_sizes; (void)n_in; (void)out_size; (void)ws_size;
  const float* x      = (const float*)d_in[0];
  const float* ln1_g  = (const float*)d_in[1];
  const float* ln1_b  = (const float*)d_in[2];
  const float* w_qkv  = (const float*)d_in[3];
  const float* b_qkv  = (const float*)d_in[4];
  const float* w_o    = (const float*)d_in[5];
  const float* b_o    = (const float*)d_in[6];
  const float* ln2_g  = (const float*)d_in[7];
  const float* ln2_b  = (const float*)d_in[8];
  const float* w_fc   = (const float*)d_in[9];
  const float* b_fc   = (const float*)d_in[10];
  const float* w_proj = (const float*)d_in[11];
  const float* b_proj = (const float*)d_in[12];
  float* out = (float*)d_out;

  char* ws = (char*)d_ws;
  const size_t MB = 1048576;
  float* x1     = (float*)(ws + 0);          // 32 MB f32 [8192][1024]
  bf16* slotA   = (bf16*)(ws + 32 * MB);     // 16 MB  h / attn / h2
  bf16* wt_qkv  = (bf16*)(ws + 48 * MB);     //  6 MB
  bf16* wt_o    = (bf16*)(ws + 54 * MB);     //  2 MB
  bf16* wt_fc   = (bf16*)(ws + 56 * MB);     //  8 MB
  bf16* wt_proj = (bf16*)(ws + 64 * MB);     //  8 MB
  bf16* qkvb    = (bf16*)(ws + 72 * MB);     // 48 MB [8192][3072]
  bf16* vtb     = (bf16*)(ws + 120 * MB);    // 16 MB
  float* p0     = (float*)(ws + 72 * MB);    // 32 MB (over qkvb, dead)
  float* p1     = (float*)(ws + 104 * MB);   // 32 MB (over qkvb/vtb, dead)
  bf16* gbuf    = (bf16*)(ws + 72 * MB);     // 64 MB (over p0/p1, dead)
  float* q1     = (float*)(ws + 32 * MB);    // 32 MB (over slotA+wt_*, dead)
  // total ws footprint: 136 MB

  dim3 blk(256);
  transpose_cast_kernel<<<dim3(3072 / 32, 1024 / 32), blk, 0, stream>>>(
      w_qkv, wt_qkv, 1024, 3072);
  transpose_cast_kernel<<<dim3(1024 / 32, 1024 / 32), blk, 0, stream>>>(
      w_o, wt_o, 1024, 1024);
  transpose_cast_kernel<<<dim3(4096 / 32, 1024 / 32), blk, 0, stream>>>(
      w_fc, wt_fc, 1024, 4096);
  transpose_cast_kernel<<<dim3(1024 / 32, 4096 / 32), blk, 0, stream>>>(
      w_proj, wt_proj, 4096, 1024);

  // LN1
  ln_kernel<<<8192, blk, 0, stream>>>(x, ln1_g, ln1_b, slotA);
  // qkv: M=8192 N=3072 K=1024 -> 32x12 = 384 blocks
  gemm256_kernel<0><<<dim3(384), dim3(512), 0, stream>>>(
      slotA, wt_qkv, b_qkv, nullptr, nullptr, qkvb, 8192, 3072, 1024, 1024,
      384);
  transpose_v_kernel<<<dim3(32, 64), blk, 0, stream>>>(qkvb, vtb);
  attn_kernel<<<dim3(64, 16), blk, 0, stream>>>(qkvb, vtb, slotA);
  // w_o split-K=2: 32x4 tiles x2 = 256 blocks, Ksub=512 -> p0,p1
  gemm256_kernel<3><<<dim3(256), dim3(512), 0, stream>>>(
      slotA, wt_o, nullptr, p0, p1, nullptr, 8192, 1024, 1024, 512, 128);
  // x1 = p0+p1+b_o+x ; h2 = LN2(x1)
  fused_ln_kernel<<<8192, blk, 0, stream>>>(p0, p1, b_o, x, ln2_g, ln2_b, x1,
                                            slotA);
  // fc: M=8192 N=4096 K=1024 -> 32x16 = 512 blocks
  gemm256_kernel<2><<<dim3(512), dim3(512), 0, stream>>>(
      slotA, wt_fc, b_fc, nullptr, nullptr, gbuf, 8192, 4096, 1024, 1024, 512);
  // proj split-K=2: 32x4 tiles x2 = 256 blocks, Ksub=2048 -> q0(d_out), q1
  gemm256_kernel<3><<<dim3(256), dim3(512), 0, stream>>>(
      gbuf, wt_proj, nullptr, out, q1, nullptr, 8192, 1024, 4096, 2048, 128);
  // out = q0 + q1 + b_proj + x1
  fused_add_kernel<<<dim3(2048), blk, 0, stream>>>(out, q1, x1, b_proj,
                                                   2097152);
}

// Round 6
// 421.692 us; speedup vs baseline: 1.1394x; 1.0545x over previous
//
#include <hip/hip_runtime.h>
#include <hip/hip_bf16.h>

using bf16 = __hip_bfloat16;
typedef __attribute__((ext_vector_type(8))) short bf16x8;
typedef __attribute__((ext_vector_type(4))) float f32x4;
typedef __attribute__((ext_vector_type(16))) float f32x16;

#define LOG2E 1.4426950408889634f

__device__ inline short f2b(float f) {
  __hip_bfloat16 h = __float2bfloat16(f);
  return *reinterpret_cast<short*>(&h);
}
__device__ inline float b2f(short s) {
  unsigned int u = ((unsigned int)(unsigned short)s) << 16;
  float f;
  __builtin_memcpy(&f, &u, 4);
  return f;
}
__device__ inline unsigned pk2(float a, float b) {
  return (unsigned)(unsigned short)f2b(a) |
         ((unsigned)(unsigned short)f2b(b) << 16);
}

// ---------------- weight transpose + cast: in[K][N] f32 -> out[N][K] bf16 ----
__global__ __launch_bounds__(256) void transpose_cast_kernel(
    const float* __restrict__ in, bf16* __restrict__ out, int K, int N) {
  __shared__ float tile[32][33];
  int tx = threadIdx.x & 31;
  int ty = threadIdx.x >> 5;
  int n0 = blockIdx.x * 32, k0 = blockIdx.y * 32;
#pragma unroll
  for (int i = 0; i < 4; i++)
    tile[ty + i * 8][tx] = in[(size_t)(k0 + ty + i * 8) * N + n0 + tx];
  __syncthreads();
#pragma unroll
  for (int i = 0; i < 4; i++)
    out[(size_t)(n0 + ty + i * 8) * K + k0 + tx] =
        __float2bfloat16(tile[tx][ty + i * 8]);
}

// ---------------- V transpose: vt[bh][d][t] ---------------------------------
__global__ __launch_bounds__(256) void transpose_v_kernel(
    const bf16* __restrict__ qkv, bf16* __restrict__ vt) {
  __shared__ short tile[64][66];
  const int bh = blockIdx.y;
  const int b = bh >> 4, h = bh & 15;
  const int t0 = blockIdx.x * 64;
  const int tid = threadIdx.x;
  const int r = tid >> 3, c8 = (tid & 7) * 8;
#pragma unroll
  for (int p = 0; p < 2; p++) {
    int t = r + p * 32;
    bf16x8 v = *(const bf16x8*)&qkv[(size_t)(b * 2048 + t0 + t) * 3072 + 2048 +
                                    h * 64 + c8];
#pragma unroll
    for (int i = 0; i < 8; i++) tile[t][c8 + i] = v[i];
  }
  __syncthreads();
#pragma unroll
  for (int p = 0; p < 2; p++) {
    int d = r + p * 32;
    int tt = c8;
    bf16x8 o;
#pragma unroll
    for (int i = 0; i < 8; i++) o[i] = tile[tt + i][d];
    *(bf16x8*)&vt[(size_t)(bh * 64 + d) * 2048 + t0 + tt] = o;
  }
}

// ---------------- LayerNorm (LN1): f32 in -> bf16 out -----------------------
__global__ __launch_bounds__(256) void ln_kernel(
    const float* __restrict__ x, const float* __restrict__ g,
    const float* __restrict__ b, bf16* __restrict__ out) {
  int row = blockIdx.x;
  const float4 v = ((const float4*)(x + (size_t)row * 1024))[threadIdx.x];
  float s = v.x + v.y + v.z + v.w;
  float ss = v.x * v.x + v.y * v.y + v.z * v.z + v.w * v.w;
#pragma unroll
  for (int off = 1; off < 64; off <<= 1) {
    s += __shfl_xor(s, off);
    ss += __shfl_xor(ss, off);
  }
  __shared__ float red[2][4];
  int w = threadIdx.x >> 6, lane = threadIdx.x & 63;
  if (lane == 0) { red[0][w] = s; red[1][w] = ss; }
  __syncthreads();
  s = red[0][0] + red[0][1] + red[0][2] + red[0][3];
  ss = red[1][0] + red[1][1] + red[1][2] + red[1][3];
  float mu = s * (1.0f / 1024.0f);
  float var = ss * (1.0f / 1024.0f) - mu * mu;
  float rstd = rsqrtf(var + 1e-5f);
  const float4 gv = ((const float4*)g)[threadIdx.x];
  const float4 bv = ((const float4*)b)[threadIdx.x];
  short4 o4;
  o4.x = f2b((v.x - mu) * rstd * gv.x + bv.x);
  o4.y = f2b((v.y - mu) * rstd * gv.y + bv.y);
  o4.z = f2b((v.z - mu) * rstd * gv.z + bv.z);
  o4.w = f2b((v.w - mu) * rstd * gv.w + bv.w);
  ((short4*)out)[(size_t)row * 256 + threadIdx.x] = o4;
}

// ---------------- fused: x1 = p0+p1+b_o+x ; h2 = LN2(x1) --------------------
__global__ __launch_bounds__(256) void fused_ln_kernel(
    const float* __restrict__ p0, const float* __restrict__ p1,
    const float* __restrict__ bo, const float* __restrict__ x,
    const float* __restrict__ g, const float* __restrict__ bln,
    float* __restrict__ x1, bf16* __restrict__ h2) {
  int row = blockIdx.x;
  size_t base = (size_t)row * 256 + threadIdx.x;
  float4 a = ((const float4*)p0)[base];
  float4 c = ((const float4*)p1)[base];
  float4 xr = ((const float4*)x)[base];
  float4 bo4 = ((const float4*)bo)[threadIdx.x];
  float4 v;
  v.x = a.x + c.x + xr.x + bo4.x;
  v.y = a.y + c.y + xr.y + bo4.y;
  v.z = a.z + c.z + xr.z + bo4.z;
  v.w = a.w + c.w + xr.w + bo4.w;
  ((float4*)x1)[base] = v;
  float s = v.x + v.y + v.z + v.w;
  float ss = v.x * v.x + v.y * v.y + v.z * v.z + v.w * v.w;
#pragma unroll
  for (int off = 1; off < 64; off <<= 1) {
    s += __shfl_xor(s, off);
    ss += __shfl_xor(ss, off);
  }
  __shared__ float red[2][4];
  int w = threadIdx.x >> 6, lane = threadIdx.x & 63;
  if (lane == 0) { red[0][w] = s; red[1][w] = ss; }
  __syncthreads();
  s = red[0][0] + red[0][1] + red[0][2] + red[0][3];
  ss = red[1][0] + red[1][1] + red[1][2] + red[1][3];
  float mu = s * (1.0f / 1024.0f);
  float var = ss * (1.0f / 1024.0f) - mu * mu;
  float rstd = rsqrtf(var + 1e-5f);
  const float4 gv = ((const float4*)g)[threadIdx.x];
  const float4 bv = ((const float4*)bln)[threadIdx.x];
  short4 o4;
  o4.x = f2b((v.x - mu) * rstd * gv.x + bv.x);
  o4.y = f2b((v.y - mu) * rstd * gv.y + bv.y);
  o4.z = f2b((v.z - mu) * rstd * gv.z + bv.z);
  o4.w = f2b((v.w - mu) * rstd * gv.w + bv.w);
  ((short4*)h2)[base] = o4;
}

// ---------------- fused: out = q0(in d_out) + q1 + b_proj + x1 --------------
__global__ __launch_bounds__(256) void fused_add_kernel(
    float* __restrict__ out, const float* __restrict__ q1,
    const float* __restrict__ x1, const float* __restrict__ bp, int n4) {
  for (int i = blockIdx.x * 256 + threadIdx.x; i < n4; i += gridDim.x * 256) {
    float4 a = ((const float4*)out)[i];
    float4 c = ((const float4*)q1)[i];
    float4 xr = ((const float4*)x1)[i];
    float4 b4 = ((const float4*)bp)[i & 255];
    float4 v;
    v.x = a.x + c.x + xr.x + b4.x;
    v.y = a.y + c.y + xr.y + b4.y;
    v.z = a.z + c.z + xr.z + b4.z;
    v.w = a.w + c.w + xr.w + b4.w;
    ((float4*)out)[i] = v;
  }
}

// ---------------- 256x256 GEMM, BK=64, 8 waves (2Mx4N, per-wave 128x64) -----
template <int EPI>
__global__ __launch_bounds__(512, 1) void gemm256_kernel(
    const bf16* __restrict__ A, const bf16* __restrict__ Bt,
    const float* __restrict__ bias, float* __restrict__ out0,
    float* __restrict__ out1, void* __restrict__ outv, int M, int N, int Kfull,
    int Ksub, int ntiles) {
  __shared__ short As[2][256 * 64];
  __shared__ short Bs[2][256 * 64];
  const int tid = threadIdx.x;
  const int lane = tid & 63, wid = tid >> 6;
  const int wr = wid >> 2, wc = wid & 3;

  const int nwg = gridDim.x;
  const int flat = blockIdx.x;
  const int sw = (flat & 7) * (nwg >> 3) + (flat >> 3);  // bijective, nwg%8==0
  const int kq = sw / ntiles;
  const int tile = sw % ntiles;
  const int gy = M >> 8;
  const int bcol = tile / gy, brow = tile % gy;
  const int koff = kq * Ksub;
  const int nk = Ksub >> 6;

  const int srow = tid >> 3;
  const int schs = (tid & 7) ^ (srow & 7);

  auto stA = [&](int kt, int buf) {
#pragma unroll
    for (int r = 0; r < 4; r++) {
      const bf16* src = A + (size_t)(brow * 256 + r * 64 + srow) * Kfull +
                        koff + kt * 64 + schs * 8;
      __builtin_amdgcn_global_load_lds(
          (const __attribute__((address_space(1))) unsigned int*)src,
          (__attribute__((address_space(3))) unsigned int*)
              &As[buf][(r * 64 + wid * 8) * 64],
          16, 0, 0);
    }
  };
  auto stB = [&](int kt, int buf) {
#pragma unroll
    for (int r = 0; r < 4; r++) {
      const bf16* src = Bt + (size_t)(bcol * 256 + r * 64 + srow) * Kfull +
                        koff + kt * 64 + schs * 8;
      __builtin_amdgcn_global_load_lds(
          (const __attribute__((address_space(1))) unsigned int*)src,
          (__attribute__((address_space(3))) unsigned int*)
              &Bs[buf][(r * 64 + wid * 8) * 64],
          16, 0, 0);
    }
  };

  f32x4 acc[8][4] = {};
  bf16x8 af[4][2], bfr[4][2];

  auto rdB = [&](int cur) {
#pragma unroll
    for (int nn = 0; nn < 4; nn++)
#pragma unroll
      for (int ks = 0; ks < 2; ks++) {
        const int row = wc * 64 + nn * 16 + (lane & 15);
        const int ch = (ks * 4 + (lane >> 4)) ^ (row & 7);
        bfr[nn][ks] = *(const bf16x8*)&Bs[cur][row * 64 + ch * 8];
      }
  };
  auto rdA = [&](int cur, int mh) {
#pragma unroll
    for (int mm = 0; mm < 4; mm++)
#pragma unroll
      for (int ks = 0; ks < 2; ks++) {
        const int row = wr * 128 + mh * 64 + mm * 16 + (lane & 15);
        const int ch = (ks * 4 + (lane >> 4)) ^ (row & 7);
        af[mm][ks] = *(const bf16x8*)&As[cur][row * 64 + ch * 8];
      }
  };

  stA(0, 0);
  stB(0, 0);
  asm volatile("s_waitcnt vmcnt(0)" ::: "memory");
  __builtin_amdgcn_s_barrier();

  for (int t = 0; t < nk; t++) {
    const int cur = t & 1, nxt = cur ^ 1;
    rdB(cur);
    rdA(cur, 0);
    if (t + 1 < nk) {
      stA(t + 1, nxt);
      stB(t + 1, nxt);
    }
    __builtin_amdgcn_s_barrier();
    asm volatile("s_waitcnt lgkmcnt(0)" ::: "memory");
    __builtin_amdgcn_sched_barrier(0);
    __builtin_amdgcn_s_setprio(1);
#pragma unroll
    for (int mm = 0; mm < 4; mm++)
#pragma unroll
      for (int nn = 0; nn < 4; nn++)
#pragma unroll
        for (int ks = 0; ks < 2; ks++)
          acc[mm][nn] = __builtin_amdgcn_mfma_f32_16x16x32_bf16(
              af[mm][ks], bfr[nn][ks], acc[mm][nn], 0, 0, 0);
    __builtin_amdgcn_s_setprio(0);
    __builtin_amdgcn_s_barrier();
    rdA(cur, 1);
    asm volatile("s_waitcnt lgkmcnt(0)" ::: "memory");
    __builtin_amdgcn_sched_barrier(0);
    __builtin_amdgcn_s_setprio(1);
#pragma unroll
    for (int mm = 0; mm < 4; mm++)
#pragma unroll
      for (int nn = 0; nn < 4; nn++)
#pragma unroll
        for (int ks = 0; ks < 2; ks++)
          acc[4 + mm][nn] = __builtin_amdgcn_mfma_f32_16x16x32_bf16(
              af[mm][ks], bfr[nn][ks], acc[4 + mm][nn], 0, 0, 0);
    __builtin_amdgcn_s_setprio(0);
    if (t + 1 < nk) asm volatile("s_waitcnt vmcnt(0)" ::: "memory");
    __builtin_amdgcn_s_barrier();
  }

#pragma unroll
  for (int m = 0; m < 8; m++)
#pragma unroll
    for (int n = 0; n < 4; n++) {
      int gr0 = brow * 256 + wr * 128 + m * 16 + (lane >> 4) * 4;
      int gc = bcol * 256 + wc * 64 + n * 16 + (lane & 15);
      if constexpr (EPI == 3) {
        float* po = kq ? out1 : out0;
#pragma unroll
        for (int j = 0; j < 4; j++)
          po[(size_t)(gr0 + j) * N + gc] = acc[m][n][j];
      } else {
        float bia = bias[gc];
#pragma unroll
        for (int j = 0; j < 4; j++) {
          float v = acc[m][n][j] + bia;
          size_t idx = (size_t)(gr0 + j) * N + gc;
          if constexpr (EPI == 0) {
            ((bf16*)outv)[idx] = __float2bfloat16(v);
          } else {
            float u = 0.7978845608028654f * (v + 0.044715f * v * v * v);
            float t2 = exp2f(u * (2.0f * LOG2E));
            float th = 1.0f - 2.0f / (t2 + 1.0f);
            ((bf16*)outv)[idx] = __float2bfloat16(0.5f * v * (1.0f + th));
          }
        }
      }
    }
}

// ---------------- Flash attention: swapped-QK^T 32x32, double-buffered ------
// Heavy-first (qt = 15 - blockIdx.y). K/V double-buffered with counted
// vmcnt(4) (next tile's 4 loads stay in flight across barriers). Tree
// max/sum; T13 defer-rescale (THR=8).
__global__ __launch_bounds__(256) void attn_kernel(
    const bf16* __restrict__ qkv, const bf16* __restrict__ vt,
    bf16* __restrict__ attn) {
  const int bh = blockIdx.x;
  const int qt = 15 - blockIdx.y;  // heavy tiles dispatch first
  const int b = bh >> 4, h = bh & 15;
  const int tid = threadIdx.x, w = tid >> 6, lane = tid & 63;
  const int col = lane & 31;
  const int hi = lane >> 5;

  __shared__ short Kl[2][64 * 64];
  __shared__ short Vl[2][64 * 64];

  const int qbase = qt * 128 + w * 32;
  const int qglob = qbase + col;
  const size_t qrow = (size_t)(b * 2048 + qglob);

  bf16x8 qf[4];
#pragma unroll
  for (int dks = 0; dks < 4; dks++) {
    bf16x8 raw =
        *(const bf16x8*)&qkv[qrow * 3072 + h * 64 + dks * 16 + hi * 8];
#pragma unroll
    for (int i = 0; i < 8; i++) qf[dks][i] = f2b(b2f(raw[i]) * 0.125f);
  }

  auto stage = [&](int kt, int buf) {
    const int kv0s = kt * 64;
#pragma unroll
    for (int j = 0; j < 2; j++) {
      int c = (j * 4 + w) * 64 + lane;
      int row = c >> 3;
      int sw8 = ((c & 7) ^ (row & 7)) * 8;
      const bf16* gk =
          qkv + (size_t)(b * 2048 + kv0s + row) * 3072 + 1024 + h * 64 + sw8;
      __builtin_amdgcn_global_load_lds(
          (const __attribute__((address_space(1))) unsigned int*)gk,
          (__attribute__((address_space(3))) unsigned int*)(
              &Kl[buf][(j * 4 + w) * 512]),
          16, 0, 0);
      const bf16* gv = vt + (size_t)(bh * 64 + row) * 2048 + kv0s + sw8;
      __builtin_amdgcn_global_load_lds(
          (const __attribute__((address_space(1))) unsigned int*)gv,
          (__attribute__((address_space(3))) unsigned int*)(
              &Vl[buf][(j * 4 + w) * 512]),
          16, 0, 0);
    }
  };

  f32x16 ot[2] = {};
  float m = -1e30f, l = 0.0f;

  const int ktend = qt * 2 + 1;
  stage(0, 0);
  for (int kt = 0; kt <= ktend; kt++) {
    const int kv0 = kt * 64;
    const int cur = kt & 1;
    if (kt < ktend) {
      stage(kt + 1, cur ^ 1);
      asm volatile("s_waitcnt vmcnt(4)" ::: "memory");
    } else {
      asm volatile("s_waitcnt vmcnt(0)" ::: "memory");
    }
    __builtin_amdgcn_s_barrier();

    if (kv0 <= qbase + 31) {
      f32x16 st[2] = {};
#pragma unroll
      for (int s = 0; s < 2; s++) {
        int kvrow = s * 32 + col;
        int swz = kvrow & 7;
#pragma unroll
        for (int dks = 0; dks < 4; dks++) {
          int ch = (dks * 2 + hi) ^ swz;
          bf16x8 kf = *(const bf16x8*)&Kl[cur][kvrow * 64 + ch * 8];
          st[s] = __builtin_amdgcn_mfma_f32_32x32x16_bf16(kf, qf[dks], st[s],
                                                          0, 0, 0);
        }
      }
      if (kv0 + 63 > qbase) {
#pragma unroll
        for (int s = 0; s < 2; s++)
#pragma unroll
          for (int r = 0; r < 16; r++) {
            int kv = kv0 + s * 32 + (r & 3) + 8 * (r >> 2) + 4 * hi;
            if (kv > qglob) st[s][r] = -1e30f;
          }
      }
      // tree max (depth 5)
      float vm[16];
#pragma unroll
      for (int i = 0; i < 16; i++) vm[i] = fmaxf(st[0][i], st[1][i]);
#pragma unroll
      for (int w2 = 8; w2 >= 1; w2 >>= 1)
#pragma unroll
        for (int i = 0; i < w2; i++) vm[i] = fmaxf(vm[i], vm[i + w2]);
      float pmax = fmaxf(vm[0], __shfl_xor(vm[0], 32));
      // T13 defer-rescale: skip O/l rescale unless max grew past THR=8
      if (!__all(pmax - m <= 8.0f)) {
        float mnew = fmaxf(m, pmax);
        float corr = exp2f((m - mnew) * LOG2E);
        m = mnew;
        l *= corr;
#pragma unroll
        for (int s = 0; s < 2; s++)
#pragma unroll
          for (int r = 0; r < 16; r++) ot[s][r] *= corr;
      }
#pragma unroll
      for (int s = 0; s < 2; s++)
#pragma unroll
        for (int r = 0; r < 16; r++)
          st[s][r] = exp2f((st[s][r] - m) * LOG2E);
      // tree sum
      float vs[16];
#pragma unroll
      for (int i = 0; i < 16; i++) vs[i] = st[0][i] + st[1][i];
#pragma unroll
      for (int w2 = 8; w2 >= 1; w2 >>= 1)
#pragma unroll
        for (int i = 0; i < w2; i++) vs[i] += vs[i + w2];
      l += vs[0] + __shfl_xor(vs[0], 32);

#pragma unroll
      for (int sub = 0; sub < 2; sub++) {
#pragma unroll
        for (int kl = 0; kl < 2; kl++) {
          unsigned A0 = pk2(st[sub][kl * 8 + 0], st[sub][kl * 8 + 1]);
          unsigned A1 = pk2(st[sub][kl * 8 + 2], st[sub][kl * 8 + 3]);
          unsigned B0 = pk2(st[sub][kl * 8 + 4], st[sub][kl * 8 + 5]);
          unsigned B1 = pk2(st[sub][kl * 8 + 6], st[sub][kl * 8 + 7]);
          unsigned sA0 = (unsigned)__shfl_xor((int)A0, 32);
          unsigned sA1 = (unsigned)__shfl_xor((int)A1, 32);
          unsigned sB0 = (unsigned)__shfl_xor((int)B0, 32);
          unsigned sB1 = (unsigned)__shfl_xor((int)B1, 32);
          union { unsigned u[4]; bf16x8 v; } pf;
          pf.u[0] = hi ? sB0 : A0;
          pf.u[1] = hi ? sB1 : A1;
          pf.u[2] = hi ? B0 : sA0;
          pf.u[3] = hi ? B1 : sA1;
          int ks = sub * 2 + kl;
#pragma unroll
          for (int ds = 0; ds < 2; ds++) {
            int drow = ds * 32 + col;
            int ch = (ks * 2 + hi) ^ (drow & 7);
            bf16x8 vf = *(const bf16x8*)&Vl[cur][drow * 64 + ch * 8];
            ot[ds] = __builtin_amdgcn_mfma_f32_32x32x16_bf16(vf, pf.v, ot[ds],
                                                             0, 0, 0);
          }
        }
      }
    }
    __builtin_amdgcn_s_barrier();
  }

  float rl = 1.0f / l;
#pragma unroll
  for (int ds = 0; ds < 2; ds++)
#pragma unroll
    for (int j = 0; j < 4; j++) {
      ushort4 o4;
      o4.x = (unsigned short)f2b(ot[ds][4 * j + 0] * rl);
      o4.y = (unsigned short)f2b(ot[ds][4 * j + 1] * rl);
      o4.z = (unsigned short)f2b(ot[ds][4 * j + 2] * rl);
      o4.w = (unsigned short)f2b(ot[ds][4 * j + 3] * rl);
      *(ushort4*)&attn[qrow * 1024 + h * 64 + 32 * ds + 8 * j + 4 * hi] = o4;
    }
}

// ---------------- host-side orchestration -----------------------------------
extern "C" void kernel_launch(void* const* d_in, const int* in_sizes, int n_in,
                              void* d_out, int out_size, void* d_ws,
                              size_t ws_size, hipStream_t stream) {
  (void)in_sizes; (void)n_in; (void)out_size; (void)ws_size;
  const float* x      = (const float*)d_in[0];
  const float* ln1_g  = (const float*)d_in[1];
  const float* ln1_b  = (const float*)d_in[2];
  const float* w_qkv  = (const float*)d_in[3];
  const float* b_qkv  = (const float*)d_in[4];
  const float* w_o    = (const float*)d_in[5];
  const float* b_o    = (const float*)d_in[6];
  const float* ln2_g  = (const float*)d_in[7];
  const float* ln2_b  = (const float*)d_in[8];
  const float* w_fc   = (const float*)d_in[9];
  const float* b_fc   = (const float*)d_in[10];
  const float* w_proj = (const float*)d_in[11];
  const float* b_proj = (const float*)d_in[12];
  float* out = (float*)d_out;

  char* ws = (char*)d_ws;
  const size_t MB = 1048576;
  float* x1     = (float*)(ws + 0);          // 32 MB f32 [8192][1024]
  bf16* slotA   = (bf16*)(ws + 32 * MB);     // 16 MB  h / attn / h2
  bf16* wt_qkv  = (bf16*)(ws + 48 * MB);     //  6 MB
  bf16* wt_o    = (bf16*)(ws + 54 * MB);     //  2 MB
  bf16* wt_fc   = (bf16*)(ws + 56 * MB);     //  8 MB
  bf16* wt_proj = (bf16*)(ws + 64 * MB);     //  8 MB
  bf16* qkvb    = (bf16*)(ws + 72 * MB);     // 48 MB [8192][3072]
  bf16* vtb     = (bf16*)(ws + 120 * MB);    // 16 MB
  float* p0     = (float*)(ws + 72 * MB);    // 32 MB (over qkvb, dead)
  float* p1     = (float*)(ws + 104 * MB);   // 32 MB (over qkvb/vtb, dead)
  bf16* gbuf    = (bf16*)(ws + 72 * MB);     // 64 MB (over p0/p1, dead)
  float* q1     = (float*)(ws + 32 * MB);    // 32 MB (over slotA+wt_*, dead)

  dim3 blk(256);
  transpose_cast_kernel<<<dim3(3072 / 32, 1024 / 32), blk, 0, stream>>>(
      w_qkv, wt_qkv, 1024, 3072);
  transpose_cast_kernel<<<dim3(1024 / 32, 1024 / 32), blk, 0, stream>>>(
      w_o, wt_o, 1024, 1024);
  transpose_cast_kernel<<<dim3(4096 / 32, 1024 / 32), blk, 0, stream>>>(
      w_fc, wt_fc, 1024, 4096);
  transpose_cast_kernel<<<dim3(1024 / 32, 4096 / 32), blk, 0, stream>>>(
      w_proj, wt_proj, 4096, 1024);

  ln_kernel<<<8192, blk, 0, stream>>>(x, ln1_g, ln1_b, slotA);
  gemm256_kernel<0><<<dim3(384), dim3(512), 0, stream>>>(
      slotA, wt_qkv, b_qkv, nullptr, nullptr, qkvb, 8192, 3072, 1024, 1024,
      384);
  transpose_v_kernel<<<dim3(32, 64), blk, 0, stream>>>(qkvb, vtb);
  attn_kernel<<<dim3(64, 16), blk, 0, stream>>>(qkvb, vtb, slotA);
  gemm256_kernel<3><<<dim3(256), dim3(512), 0, stream>>>(
      slotA, wt_o, nullptr, p0, p1, nullptr, 8192, 1024, 1024, 512, 128);
  fused_ln_kernel<<<8192, blk, 0, stream>>>(p0, p1, b_o, x, ln2_g, ln2_b, x1,
                                            slotA);
  gemm256_kernel<2><<<dim3(512), dim3(512), 0, stream>>>(
      slotA, wt_fc, b_fc, nullptr, nullptr, gbuf, 8192, 4096, 1024, 1024, 512);
  gemm256_kernel<3><<<dim3(256), dim3(512), 0, stream>>>(
      gbuf, wt_proj, nullptr, out, q1, nullptr, 8192, 1024, 4096, 2048, 128);
  fused_add_kernel<<<dim3(2048), blk, 0, stream>>>(out, q1, x1, b_proj,
                                                   2097152);
}